// Round 5
// baseline (277.696 us; speedup 1.0000x reference)
//
#include <hip/hip_runtime.h>
#include <hip/hip_bf16.h>
#include <cstddef>
#include <cstdint>

// GINConvFFT round 17: r16 + split-K tail fusion: bn_part is folded into
// ysum (fence+atomic last-block-per-r-tile sums the 4 K-quarters, writes
// final Y and the per-tile sum/sumsq partials). bn_out reads Y directly.
// Chain is now 4 kernels: prep2 -> zmsq -> ysum -> bn_out.
//   prep2: MallC even col-slices=(1+eps)I+A_s; MT; Wt; zero cnt (1280 blk)
//   zmsq : blocks 0-255: Z[(b*64+o)][k*512+m] = Wt . x_b^T (fused k)
//          blocks 256-383: MallC odd slices = M_s^2 (64x64 tiles)
//   ysum : Yh[kq][r][o] quarter partials; last block per r-tile sums ->
//          Y + part (sum/sumsq)                              (1024 blk)
//   bn_out : inline stats + normalize+relu+w2+b2             (256 blk)
#define B_   32
#define N_   512
#define D_   768
#define OUT_ 64
#define R_   (B_ * N_)

typedef unsigned short u16;
typedef __bf16 bf16x8 __attribute__((ext_vector_type(8)));
typedef float  f32x4  __attribute__((ext_vector_type(4)));
typedef unsigned short u16x8 __attribute__((ext_vector_type(8)));

__device__ __forceinline__ u16 f2bf(float f) {
    __hip_bfloat16 h = __float2bfloat16(f);
    return __builtin_bit_cast(u16, h);
}

__device__ __forceinline__ f32x4 mfma16(u16x8 a, u16x8 b, f32x4 c) {
    return __builtin_amdgcn_mfma_f32_16x16x32_bf16(
        __builtin_bit_cast(bf16x8, a), __builtin_bit_cast(bf16x8, b), c, 0, 0, 0);
}

__device__ __forceinline__ void gl2lds16(const void* g, void* l) {
    __builtin_amdgcn_global_load_lds(
        (const __attribute__((address_space(1))) unsigned int*)g,
        (__attribute__((address_space(3))) unsigned int*)l, 16, 0, 0);
}

// ---------------------------------------------------------------------------
// prep2: [0,512) build M (even MallC col slices) + MT | [512,1280) build Wt
//        block 0 additionally zeroes the 256 split-K counters.
// ---------------------------------------------------------------------------
__global__ __launch_bounds__(256) void prep2(
    const float* __restrict__ support, const float* __restrict__ weight,
    const float* __restrict__ epsp,
    u16* __restrict__ MallC, u16* __restrict__ MT, u16* __restrict__ Wt,
    int* __restrict__ cnt)
{
    const int blk = blockIdx.x, tid = threadIdx.x;
    __shared__ float t[32][33];
    if (blk == 0) cnt[tid] = 0;                     // 256 counters
    if (blk < 512) {
        int s = blk >> 8, rem = blk & 255;
        int n0 = (rem >> 4) * 32, m0 = (rem & 15) * 32;
        const float f = 1.0f + epsp[0];
        const float* S = support + (size_t)s * 262144;
#pragma unroll
        for (int p = 0; p < 4; ++p) {
            int nl = p * 8 + (tid >> 5), ml = tid & 31;
            float v = S[(size_t)(n0 + nl) * 512 + m0 + ml];
            if (n0 + nl == m0 + ml) v += f;
            MallC[(size_t)(n0 + nl) * 2048 + s * 1024 + m0 + ml] = f2bf(v);
            t[nl][ml] = v;
        }
        __syncthreads();
#pragma unroll
        for (int p = 0; p < 4; ++p) {
            int ml = p * 8 + (tid >> 5), nl = tid & 31;
            MT[(size_t)s * 262144 + (size_t)(m0 + ml) * 512 + n0 + nl] = f2bf(t[nl][ml]);
        }
    } else {
        int idx = (blk - 512) * 256 + tid;          // 4*64*768 = 196608
        int k = idx / 49152, rem = idx % 49152;
        int o = rem / 768, d = rem % 768;
        int l = d >> 6, hh = d & 63;
        Wt[idx] = f2bf(weight[((size_t)l * 256 + hh * 4 + k) * 64 + o]);
    }
}

// ---------------------------------------------------------------------------
// zmsq: fused-k zgemm + msq, 80 KB LDS, 2 blocks/CU max.
//  blocks 0-255: zgemm. b = bid>>3, m0 = (bid&7)*64.
//    A = full Wt [256 (k,o)][768] (gl2lds, 32 KB/iter), B = x rows m0..+63
//    (fp32 -> cvt in VGPR -> LDS, 8 KB/iter). K=768, BK=64, 12 iters.
//    Per iter: sync -> prefetch(kk+1) -> MFMA(kk) -> cvt+write B(kk+1).
//  blocks 256-383: msq (64x64 tiles of M_s^2), same reordered pipeline.
// ---------------------------------------------------------------------------
__global__ __launch_bounds__(256, 2) void zmsq(
    const u16* __restrict__ Wt, const float* __restrict__ x,
    const u16* __restrict__ MallC_in, const u16* __restrict__ MT,
    u16* __restrict__ Z, u16* __restrict__ MallC_out)
{
    __shared__ __align__(16) u16 SM[40960];          // 80 KB
    const int tid = threadIdx.x, lane = tid & 63, wid = tid >> 6;
    const int lrow = lane & 15, lk8 = (lane >> 4) * 8;
    const int q = lane >> 4;
    const int bid = blockIdx.x;

    if (bid < 256) {
        // ---------------- fused-k zgemm ----------------
        const int b = bid >> 3, m0 = (bid & 7) * 64;
        u16* Abuf = SM;
        u16* Bbuf = SM + 32768;

        // A staging: 32 subtiles (p 0-1 x g 0-15), 8 per wave.
        const u16* gsrcA[8]; u16* ldstA[8];
#pragma unroll
        for (int t = 0; t < 8; ++t) {
            int idx = wid * 8 + t;                   // [0,32)
            int p = idx >> 4, g = idx & 15;
            gsrcA[t] = Wt + (size_t)(g * 16 + lrow) * 768 + p * 32 + lk8;
            ldstA[t] = Abuf + p * 8192 + g * 512;
        }
        // B: thread t -> row r = t>>2 (64 m-rows), c4 = t&3 (16 consec floats)
        const int r = tid >> 2, c4 = tid & 3;
        const float* gx = x + (size_t)(b * 512 + m0 + r) * 768 + c4 * 16;
        u16* bdst = Bbuf + (c4 >> 1) * 2048 + (r >> 4) * 512
                  + (c4 & 1) * 256 + (r & 15) * 8;

        f32x4 acc[4][4] = {};

        // ---- prologue: stage tile 0 into buf 0 (no sync yet) ----
        {
            f32x4 a0 = *(const f32x4*)(gx);
            f32x4 a1 = *(const f32x4*)(gx + 4);
            f32x4 a2 = *(const f32x4*)(gx + 8);
            f32x4 a3 = *(const f32x4*)(gx + 12);
#pragma unroll
            for (int t = 0; t < 8; ++t) gl2lds16(gsrcA[t], ldstA[t]);
            u16x8 w0, w1;
#pragma unroll
            for (int j = 0; j < 4; ++j) {
                w0[j] = f2bf(a0[j]); w0[4 + j] = f2bf(a1[j]);
                w1[j] = f2bf(a2[j]); w1[4 + j] = f2bf(a3[j]);
            }
            *(u16x8*)(bdst)       = w0;
            *(u16x8*)(bdst + 128) = w1;
        }

        // ---- main loop: sync -> prefetch(kk+1) -> MFMA(kk) -> write B ----
#pragma unroll 2
        for (int kk = 0; kk < 12; ++kk) {
            const int cbA = (kk & 1) * 16384, nbA = cbA ^ 16384;
            const int cbB = (kk & 1) * 4096,  nbB = cbB ^ 4096;
            __syncthreads();                 // waits tile kk's loads only
            f32x4 a0, a1, a2, a3;
            if (kk < 11) {
                const float* g = gx + (kk + 1) * 64;
                a0 = *(const f32x4*)(g);
                a1 = *(const f32x4*)(g + 4);
                a2 = *(const f32x4*)(g + 8);
                a3 = *(const f32x4*)(g + 12);
#pragma unroll
                for (int t = 0; t < 8; ++t)
                    gl2lds16(gsrcA[t] + (kk + 1) * 64, ldstA[t] + nbA);
            }
#pragma unroll
            for (int p = 0; p < 2; ++p) {
                u16x8 af[4], bq[4];
#pragma unroll
                for (int f = 0; f < 4; ++f)
                    af[f] = *(const u16x8*)(Abuf + cbA + p * 8192 + (wid * 4 + f) * 512 + lane * 8);
#pragma unroll
                for (int f = 0; f < 4; ++f)
                    bq[f] = *(const u16x8*)(Bbuf + cbB + p * 2048 + f * 512 + lane * 8);
#pragma unroll
                for (int fi = 0; fi < 4; ++fi)
#pragma unroll
                    for (int fj = 0; fj < 4; ++fj)
                        acc[fi][fj] = mfma16(af[fi], bq[fj], acc[fi][fj]);
            }
            if (kk < 11) {
                u16x8 w0, w1;
#pragma unroll
                for (int j = 0; j < 4; ++j) {
                    w0[j] = f2bf(a0[j]); w0[4 + j] = f2bf(a1[j]);
                    w1[j] = f2bf(a2[j]); w1[4 + j] = f2bf(a3[j]);
                }
                *(u16x8*)(bdst + nbB)       = w0;
                *(u16x8*)(bdst + nbB + 128) = w1;
            }
        }
        __syncthreads();                     // all MFMA reads done before reuse

        // ---- epilogue: repack [256 rows][72 stride] in LDS, coalesced store
        u16* scr = SM;
#pragma unroll
        for (int fi = 0; fi < 4; ++fi)
#pragma unroll
            for (int fj = 0; fj < 4; ++fj)
#pragma unroll
                for (int rr = 0; rr < 4; ++rr)
                    scr[(wid * 64 + fi * 16 + q * 4 + rr) * 72 + fj * 16 + lrow]
                        = f2bf(acc[fi][fj][rr]);
        __syncthreads();
        // 8 threads per row (8 x 8 u16 = 64 cols), 32 rows per pass, 8 passes.
        const int c8 = (tid & 7) * 8, rg = tid >> 3;     // rg in [0,32)
#pragma unroll
        for (int i = 0; i < 8; ++i) {
            int srow = i * 32 + rg;                      // [0,256)
            u16x8 v = *(const u16x8*)(scr + srow * 72 + c8);
            int o = srow & 63, k = srow >> 6;
            *(u16x8*)(Z + (size_t)(b * 64 + o) * 2048 + k * 512 + m0 + c8) = v;
        }
    } else {
        // ---------------- msq ----------------
        const int lb = bid - 256;
        const int s = lb >> 6, i0 = ((lb >> 3) & 7) * 64, j0 = (lb & 7) * 64;
        const int wr = wid >> 1, wc = wid & 1;

        const u16* gsrc[4]; u16* ldst[4];
#pragma unroll
        for (int t = 0; t < 4; ++t) {
            int idx = wid * 4 + t;                   // [0,16)
            if (idx < 8) {
                int p = idx >> 2, sub = idx & 3;
                gsrc[t] = MallC_in + (size_t)(i0 + sub * 16 + lrow) * 2048 + s * 1024 + p * 32 + lk8;
                ldst[t] = SM + p * 2048 + sub * 512;
            } else {
                int i2 = idx - 8;
                int p = i2 >> 2, sub = i2 & 3;
                gsrc[t] = MT + (size_t)s * 262144 + (size_t)(j0 + sub * 16 + lrow) * 512 + p * 32 + lk8;
                ldst[t] = SM + 4096 + p * 2048 + sub * 512;
            }
        }
        f32x4 acc[2][2] = {};
        // prologue: stage tile 0 into buf 0 (no sync yet)
#pragma unroll
        for (int t = 0; t < 4; ++t) gl2lds16(gsrc[t], ldst[t]);
#pragma unroll 2
        for (int kk = 0; kk < 8; ++kk) {
            const int cb = (kk & 1) * 8192, nb = cb ^ 8192;
            __syncthreads();                 // waits tile kk's loads only
            if (kk < 7) {
#pragma unroll
                for (int t = 0; t < 4; ++t)
                    gl2lds16(gsrc[t] + (kk + 1) * 64, ldst[t] + nb);
            }
#pragma unroll
            for (int p = 0; p < 2; ++p) {
                u16x8 af[2], bq[2];
#pragma unroll
                for (int f = 0; f < 2; ++f)
                    af[f] = *(const u16x8*)(SM + cb + p * 2048 + (wr * 2 + f) * 512 + lane * 8);
#pragma unroll
                for (int f = 0; f < 2; ++f)
                    bq[f] = *(const u16x8*)(SM + cb + 4096 + p * 2048 + (wc * 2 + f) * 512 + lane * 8);
#pragma unroll
                for (int fi = 0; fi < 2; ++fi)
#pragma unroll
                    for (int fj = 0; fj < 2; ++fj)
                        acc[fi][fj] = mfma16(af[fi], bq[fj], acc[fi][fj]);
            }
        }
#pragma unroll
        for (int fi = 0; fi < 2; ++fi)
#pragma unroll
            for (int fj = 0; fj < 2; ++fj)
#pragma unroll
                for (int rr = 0; rr < 4; ++rr) {
                    int n = i0 + wr * 32 + fi * 16 + q * 4 + rr;
                    int c = j0 + wc * 32 + fj * 16 + lrow;
                    MallC_out[(size_t)n * 2048 + (2 * s + 1) * 512 + c] = f2bf(acc[fi][fj][rr]);
                }
    }
}

// ---------------------------------------------------------------------------
// ysum: 1024 blocks (4/CU). kq = bid>>8, rt = bid&255: r0 = rt*64, b = rt>>3,
// n0 = r0&511. Tile 64r x 64o, K=512 (quarter), BK=64, 8 iters.
// Split-K tail: 4th block per rt sums quarters -> Y + part (bn_part fused).
// ---------------------------------------------------------------------------
__global__ __launch_bounds__(256, 4) void ysum(
    const u16* __restrict__ G, const u16* __restrict__ Z,
    float* __restrict__ Yh, float* __restrict__ Y,
    float* __restrict__ part, int* __restrict__ cnt)
{
    __shared__ __align__(16) u16 SM[16384];          // 32 KB, 2 buffers
    __shared__ int amLast;
    const int tid = threadIdx.x, lane = tid & 63, wid = tid >> 6;
    const int wr = wid >> 1, wc = wid & 1;
    const int lrow = lane & 15, lk8 = (lane >> 4) * 8;
    const int bid = blockIdx.x;
    const int kq = bid >> 8, rt = bid & 255;
    const int r0 = rt * 64, b = rt >> 3, n0 = r0 & 511;

    const u16* gsrc[4]; u16* ldst[4];
#pragma unroll
    for (int t = 0; t < 4; ++t) {
        int idx = wid * 4 + t;
        if (idx < 8) {
            int p = idx >> 2, sub = idx & 3;
            gsrc[t] = G + (size_t)(n0 + sub * 16 + lrow) * 2048 + kq * 512 + p * 32 + lk8;
            ldst[t] = SM + p * 2048 + sub * 512;
        } else {
            int i2 = idx - 8;
            int p = i2 >> 2, sub = i2 & 3;
            gsrc[t] = Z + (size_t)(b * 64 + sub * 16 + lrow) * 2048 + kq * 512 + p * 32 + lk8;
            ldst[t] = SM + 4096 + p * 2048 + sub * 512;
        }
    }
    f32x4 acc[2][2] = {};
    // prologue: stage tile 0 into buf 0 (no sync yet)
#pragma unroll
    for (int t = 0; t < 4; ++t) gl2lds16(gsrc[t], ldst[t]);
#pragma unroll 2
    for (int kk = 0; kk < 8; ++kk) {
        const int cb = (kk & 1) * 8192, nb = cb ^ 8192;
        __syncthreads();                     // waits tile kk's loads only
        if (kk < 7) {
#pragma unroll
            for (int t = 0; t < 4; ++t)
                gl2lds16(gsrc[t] + (kk + 1) * 64, ldst[t] + nb);
        }
#pragma unroll
        for (int p = 0; p < 2; ++p) {
            u16x8 af[2], bq[2];
#pragma unroll
            for (int f = 0; f < 2; ++f)
                af[f] = *(const u16x8*)(SM + cb + p * 2048 + (wr * 2 + f) * 512 + lane * 8);
#pragma unroll
            for (int f = 0; f < 2; ++f)
                bq[f] = *(const u16x8*)(SM + cb + 4096 + p * 2048 + (wc * 2 + f) * 512 + lane * 8);
#pragma unroll
            for (int fi = 0; fi < 2; ++fi)
#pragma unroll
                for (int fj = 0; fj < 2; ++fj)
                    acc[fi][fj] = mfma16(af[fi], bq[fj], acc[fi][fj]);
        }
    }
    const int q = lane >> 4;
    float* Yk = Yh + (size_t)kq * R_ * 64;
#pragma unroll
    for (int fi = 0; fi < 2; ++fi)
#pragma unroll
        for (int fj = 0; fj < 2; ++fj)
#pragma unroll
            for (int rr = 0; rr < 4; ++rr) {
                int r2 = r0 + wr * 32 + fi * 16 + q * 4 + rr;
                int o  = wc * 32 + fj * 16 + lrow;
                Yk[(size_t)r2 * 64 + o] = acc[fi][fj][rr];
            }

    // ---- split-K tail: last block per r-tile sums quarters, emits stats ----
    __threadfence();                         // publish Yh writes device-wide
    if (tid == 0) amLast = (atomicAdd(&cnt[rt], 1) == 3);
    __syncthreads();                         // amLast visible; SM reads done
    if (amLast) {
        const int o = tid & 63, g = tid >> 6;
        float s = 0.f, s2 = 0.f;
#pragma unroll
        for (int p = 0; p < 16; ++p) {
            int r = r0 + p * 4 + g;
            size_t off = (size_t)r * 64 + o;
            float v = Yh[off] + Yh[(size_t)R_ * 64 + off]
                    + Yh[(size_t)2 * R_ * 64 + off] + Yh[(size_t)3 * R_ * 64 + off];
            Y[off] = v;
            s += v; s2 += v * v;
        }
        float* ls  = (float*)SM;             // 256 floats
        float* ls2 = ls + 256;
        ls[g * 64 + o] = s; ls2[g * 64 + o] = s2;
        __syncthreads();
        if (tid < 64) {
            float t  = ls[tid] + ls[64 + tid] + ls[128 + tid] + ls[192 + tid];
            float t2 = ls2[tid] + ls2[64 + tid] + ls2[128 + tid] + ls2[192 + tid];
            part[rt * 128 + tid]      = t;
            part[rt * 128 + 64 + tid] = t2;
        }
    }
}

// ---------------------------------------------------------------------------
// bn_out: inline stats from partials, then normalize+relu+w2+b2 (reads Y).
// ---------------------------------------------------------------------------
__global__ __launch_bounds__(256) void bn_out(
    const float* __restrict__ Y, const float* __restrict__ part,
    const float* __restrict__ gamma, const float* __restrict__ beta,
    const float* __restrict__ w2, const float* __restrict__ b2,
    float* __restrict__ out)
{
    __shared__ float ys[64 * 68];
    __shared__ float w2s[64 * 65];
    __shared__ float red[4][64], red2[4][64];
    __shared__ float sa[64], sh[64];
    const int tid = threadIdx.x;
    const int r0 = blockIdx.x * 64;
    const int o = tid & 63, g = tid >> 6;
    {
        float s = 0.f, s2 = 0.f;
        for (int p = g; p < 256; p += 4) {
            s  += part[p * 128 + o];
            s2 += part[p * 128 + 64 + o];
        }
        red[g][o] = s; red2[g][o] = s2;
    }
#pragma unroll
    for (int i = 0; i < 16; ++i) {
        int idx = tid + i * 256;
        w2s[(idx >> 6) * 65 + (idx & 63)] = w2[idx];
    }
    __syncthreads();
    if (tid < 64) {
        float t0 = red[0][tid] + red[1][tid] + red[2][tid] + red[3][tid];
        float t2 = red2[0][tid] + red2[1][tid] + red2[2][tid] + red2[3][tid];
        float mean = t0 * (1.0f / R_);
        float var  = t2 * (1.0f / R_) - mean * mean;
        float a = rsqrtf(var + 1e-5f) * gamma[tid];
        sa[tid] = a;
        sh[tid] = beta[tid] - mean * a;
    }
    __syncthreads();
    {
        float a = sa[o], bsh = sh[o];
#pragma unroll
        for (int p = 0; p < 16; ++p) {
            int rl = p * 4 + g;
            size_t off = (size_t)(r0 + rl) * 64 + o;
            float v = Y[off];
            ys[o * 68 + rl] = fmaxf(fmaf(v, a, bsh), 0.f);
        }
    }
    __syncthreads();
    float acc[16];
    float bb = b2[o];
#pragma unroll
    for (int j = 0; j < 16; ++j) acc[j] = bb;
    for (int c = 0; c < 64; ++c) {
        float wv = w2s[o * 65 + c];
        const float* yr = ys + c * 68 + g * 16;
        f32x4 y0 = *(const f32x4*)(yr);
        f32x4 y1 = *(const f32x4*)(yr + 4);
        f32x4 y2 = *(const f32x4*)(yr + 8);
        f32x4 y3 = *(const f32x4*)(yr + 12);
#pragma unroll
        for (int j = 0; j < 4; ++j) {
            acc[j]      = fmaf(wv, y0[j], acc[j]);
            acc[4 + j]  = fmaf(wv, y1[j], acc[4 + j]);
            acc[8 + j]  = fmaf(wv, y2[j], acc[8 + j]);
            acc[12 + j] = fmaf(wv, y3[j], acc[12 + j]);
        }
    }
#pragma unroll
    for (int j = 0; j < 16; ++j)
        out[(size_t)(r0 + g * 16 + j) * OUT_ + o] = acc[j];
}

// ---------------------------------------------------------------------------
extern "C" void kernel_launch(void* const* d_in, const int* in_sizes, int n_in,
                              void* d_out, int out_size, void* d_ws, size_t ws_size,
                              hipStream_t stream)
{
    const float* x       = (const float*)d_in[0];
    const float* support = (const float*)d_in[1];
    const float* weight  = (const float*)d_in[2];
    const float* eps     = (const float*)d_in[3];
    const float* gamma   = (const float*)d_in[4];
    const float* beta    = (const float*)d_in[5];
    const float* w2      = (const float*)d_in[6];
    const float* b2      = (const float*)d_in[7];
    float* out = (float*)d_out;

    char* ws = (char*)d_ws;
    u16*   MallC = (u16*)(ws);                      //  2,097,152  [512][2048]
    u16*   MT    = (u16*)(ws + 2097152);            //  1,048,576
    u16*   Wt    = (u16*)(ws + 3145728);            //    393,216  [256][768]
    u16*   Z     = (u16*)(ws + 3538944);            //  8,388,608  [2048][2048]
    float* Yh    = (float*)(ws + 11927552);         // 16,777,216  (4 quarters)
    float* part  = (float*)(ws + 28704768);         //    131,072
    float* Y     = (float*)(ws + 28835840);         //  4,194,304  [16384][64]
    int*   cnt   = (int*)  (ws + 33030144);         //      1,024  [256]

    prep2  <<<1280, 256, 0, stream>>>(support, weight, eps, MallC, MT, Wt, cnt);
    zmsq   <<<384,  256, 0, stream>>>(Wt, x, MallC, MT, Z, MallC);
    ysum   <<<1024, 256, 0, stream>>>(MallC, Z, Yh, Y, part, cnt);
    bn_out <<<256,  256, 0, stream>>>(Y, part, gamma, beta, w2, b2, out);
}

// Round 6
// 163.381 us; speedup vs baseline: 1.6997x; 1.6997x over previous
//
#include <hip/hip_runtime.h>
#include <hip/hip_bf16.h>
#include <cstddef>
#include <cstdint>

// GINConvFFT round 18: revert to r16 (fence-free, 164.6 us) + cheap bn-chain
// traffic cut: bn_part also writes Y = sum of 4 quarters (it computes v
// anyway); bn_out reads Y once instead of re-summing 4 quarters
// (-12.6 MB read, +4.2 MB write). NO cross-block fences (r17 lesson:
// per-block __threadfence on gfx950 = serialized L2 writeback storm,
// +100ns each, +113 us total).
//   prep2: MallC even col-slices=(1+eps)I+A_s; MT; Wt          (1280 blk)
//   zmsq : blocks 0-255: Z[(b*64+o)][k*512+m] = Wt . x_b^T (fused k)
//          blocks 256-383: MallC odd slices = M_s^2 (64x64 tiles)
//   ysum : Yh[kq][r][o] = quarter-K partial of MallC . Z^T     (1024 blk)
//   bn_part: per-64-row partials + Y = sum of quarters         (256 blk)
//   bn_out : inline stats + normalize+relu+w2+b2 (reads Y)     (256 blk)
#define B_   32
#define N_   512
#define D_   768
#define OUT_ 64
#define R_   (B_ * N_)

typedef unsigned short u16;
typedef __bf16 bf16x8 __attribute__((ext_vector_type(8)));
typedef float  f32x4  __attribute__((ext_vector_type(4)));
typedef unsigned short u16x8 __attribute__((ext_vector_type(8)));

__device__ __forceinline__ u16 f2bf(float f) {
    __hip_bfloat16 h = __float2bfloat16(f);
    return __builtin_bit_cast(u16, h);
}

__device__ __forceinline__ f32x4 mfma16(u16x8 a, u16x8 b, f32x4 c) {
    return __builtin_amdgcn_mfma_f32_16x16x32_bf16(
        __builtin_bit_cast(bf16x8, a), __builtin_bit_cast(bf16x8, b), c, 0, 0, 0);
}

__device__ __forceinline__ void gl2lds16(const void* g, void* l) {
    __builtin_amdgcn_global_load_lds(
        (const __attribute__((address_space(1))) unsigned int*)g,
        (__attribute__((address_space(3))) unsigned int*)l, 16, 0, 0);
}

// ---------------------------------------------------------------------------
// prep2: [0,512) build M (even MallC col slices) + MT | [512,1280) build Wt
// ---------------------------------------------------------------------------
__global__ __launch_bounds__(256) void prep2(
    const float* __restrict__ support, const float* __restrict__ weight,
    const float* __restrict__ epsp,
    u16* __restrict__ MallC, u16* __restrict__ MT, u16* __restrict__ Wt)
{
    const int blk = blockIdx.x, tid = threadIdx.x;
    __shared__ float t[32][33];
    if (blk < 512) {
        int s = blk >> 8, rem = blk & 255;
        int n0 = (rem >> 4) * 32, m0 = (rem & 15) * 32;
        const float f = 1.0f + epsp[0];
        const float* S = support + (size_t)s * 262144;
#pragma unroll
        for (int p = 0; p < 4; ++p) {
            int nl = p * 8 + (tid >> 5), ml = tid & 31;
            float v = S[(size_t)(n0 + nl) * 512 + m0 + ml];
            if (n0 + nl == m0 + ml) v += f;
            MallC[(size_t)(n0 + nl) * 2048 + s * 1024 + m0 + ml] = f2bf(v);
            t[nl][ml] = v;
        }
        __syncthreads();
#pragma unroll
        for (int p = 0; p < 4; ++p) {
            int ml = p * 8 + (tid >> 5), nl = tid & 31;
            MT[(size_t)s * 262144 + (size_t)(m0 + ml) * 512 + n0 + nl] = f2bf(t[nl][ml]);
        }
    } else {
        int idx = (blk - 512) * 256 + tid;          // 4*64*768 = 196608
        int k = idx / 49152, rem = idx % 49152;
        int o = rem / 768, d = rem % 768;
        int l = d >> 6, hh = d & 63;
        Wt[idx] = f2bf(weight[((size_t)l * 256 + hh * 4 + k) * 64 + o]);
    }
}

// ---------------------------------------------------------------------------
// zmsq: fused-k zgemm + msq, 80 KB LDS, 2 blocks/CU max.
//  blocks 0-255: zgemm. b = bid>>3, m0 = (bid&7)*64.
//    A = full Wt [256 (k,o)][768] (gl2lds, 32 KB/iter), B = x rows m0..+63
//    (fp32 -> cvt in VGPR -> LDS, 8 KB/iter). K=768, BK=64, 12 iters.
//    Per iter: sync -> prefetch(kk+1) -> MFMA(kk) -> cvt+write B(kk+1).
//  blocks 256-383: msq (64x64 tiles of M_s^2), same reordered pipeline.
// ---------------------------------------------------------------------------
__global__ __launch_bounds__(256, 2) void zmsq(
    const u16* __restrict__ Wt, const float* __restrict__ x,
    const u16* __restrict__ MallC_in, const u16* __restrict__ MT,
    u16* __restrict__ Z, u16* __restrict__ MallC_out)
{
    __shared__ __align__(16) u16 SM[40960];          // 80 KB
    const int tid = threadIdx.x, lane = tid & 63, wid = tid >> 6;
    const int lrow = lane & 15, lk8 = (lane >> 4) * 8;
    const int q = lane >> 4;
    const int bid = blockIdx.x;

    if (bid < 256) {
        // ---------------- fused-k zgemm ----------------
        const int b = bid >> 3, m0 = (bid & 7) * 64;
        u16* Abuf = SM;
        u16* Bbuf = SM + 32768;

        // A staging: 32 subtiles (p 0-1 x g 0-15), 8 per wave.
        const u16* gsrcA[8]; u16* ldstA[8];
#pragma unroll
        for (int t = 0; t < 8; ++t) {
            int idx = wid * 8 + t;                   // [0,32)
            int p = idx >> 4, g = idx & 15;
            gsrcA[t] = Wt + (size_t)(g * 16 + lrow) * 768 + p * 32 + lk8;
            ldstA[t] = Abuf + p * 8192 + g * 512;
        }
        // B: thread t -> row r = t>>2 (64 m-rows), c4 = t&3 (16 consec floats)
        const int r = tid >> 2, c4 = tid & 3;
        const float* gx = x + (size_t)(b * 512 + m0 + r) * 768 + c4 * 16;
        u16* bdst = Bbuf + (c4 >> 1) * 2048 + (r >> 4) * 512
                  + (c4 & 1) * 256 + (r & 15) * 8;

        f32x4 acc[4][4] = {};

        // ---- prologue: stage tile 0 into buf 0 (no sync yet) ----
        {
            f32x4 a0 = *(const f32x4*)(gx);
            f32x4 a1 = *(const f32x4*)(gx + 4);
            f32x4 a2 = *(const f32x4*)(gx + 8);
            f32x4 a3 = *(const f32x4*)(gx + 12);
#pragma unroll
            for (int t = 0; t < 8; ++t) gl2lds16(gsrcA[t], ldstA[t]);
            u16x8 w0, w1;
#pragma unroll
            for (int j = 0; j < 4; ++j) {
                w0[j] = f2bf(a0[j]); w0[4 + j] = f2bf(a1[j]);
                w1[j] = f2bf(a2[j]); w1[4 + j] = f2bf(a3[j]);
            }
            *(u16x8*)(bdst)       = w0;
            *(u16x8*)(bdst + 128) = w1;
        }

        // ---- main loop: sync -> prefetch(kk+1) -> MFMA(kk) -> write B ----
#pragma unroll 2
        for (int kk = 0; kk < 12; ++kk) {
            const int cbA = (kk & 1) * 16384, nbA = cbA ^ 16384;
            const int cbB = (kk & 1) * 4096,  nbB = cbB ^ 4096;
            __syncthreads();                 // waits tile kk's loads only
            f32x4 a0, a1, a2, a3;
            if (kk < 11) {
                const float* g = gx + (kk + 1) * 64;
                a0 = *(const f32x4*)(g);
                a1 = *(const f32x4*)(g + 4);
                a2 = *(const f32x4*)(g + 8);
                a3 = *(const f32x4*)(g + 12);
#pragma unroll
                for (int t = 0; t < 8; ++t)
                    gl2lds16(gsrcA[t] + (kk + 1) * 64, ldstA[t] + nbA);
            }
#pragma unroll
            for (int p = 0; p < 2; ++p) {
                u16x8 af[4], bq[4];
#pragma unroll
                for (int f = 0; f < 4; ++f)
                    af[f] = *(const u16x8*)(Abuf + cbA + p * 8192 + (wid * 4 + f) * 512 + lane * 8);
#pragma unroll
                for (int f = 0; f < 4; ++f)
                    bq[f] = *(const u16x8*)(Bbuf + cbB + p * 2048 + f * 512 + lane * 8);
#pragma unroll
                for (int fi = 0; fi < 4; ++fi)
#pragma unroll
                    for (int fj = 0; fj < 4; ++fj)
                        acc[fi][fj] = mfma16(af[fi], bq[fj], acc[fi][fj]);
            }
            if (kk < 11) {
                u16x8 w0, w1;
#pragma unroll
                for (int j = 0; j < 4; ++j) {
                    w0[j] = f2bf(a0[j]); w0[4 + j] = f2bf(a1[j]);
                    w1[j] = f2bf(a2[j]); w1[4 + j] = f2bf(a3[j]);
                }
                *(u16x8*)(bdst + nbB)       = w0;
                *(u16x8*)(bdst + nbB + 128) = w1;
            }
        }
        __syncthreads();                     // all MFMA reads done before reuse

        // ---- epilogue: repack [256 rows][72 stride] in LDS, coalesced store
        u16* scr = SM;
#pragma unroll
        for (int fi = 0; fi < 4; ++fi)
#pragma unroll
            for (int fj = 0; fj < 4; ++fj)
#pragma unroll
                for (int rr = 0; rr < 4; ++rr)
                    scr[(wid * 64 + fi * 16 + q * 4 + rr) * 72 + fj * 16 + lrow]
                        = f2bf(acc[fi][fj][rr]);
        __syncthreads();
        // 8 threads per row (8 x 8 u16 = 64 cols), 32 rows per pass, 8 passes.
        const int c8 = (tid & 7) * 8, rg = tid >> 3;     // rg in [0,32)
#pragma unroll
        for (int i = 0; i < 8; ++i) {
            int srow = i * 32 + rg;                      // [0,256)
            u16x8 v = *(const u16x8*)(scr + srow * 72 + c8);
            int o = srow & 63, k = srow >> 6;
            *(u16x8*)(Z + (size_t)(b * 64 + o) * 2048 + k * 512 + m0 + c8) = v;
        }
    } else {
        // ---------------- msq ----------------
        const int lb = bid - 256;
        const int s = lb >> 6, i0 = ((lb >> 3) & 7) * 64, j0 = (lb & 7) * 64;
        const int wr = wid >> 1, wc = wid & 1;

        const u16* gsrc[4]; u16* ldst[4];
#pragma unroll
        for (int t = 0; t < 4; ++t) {
            int idx = wid * 4 + t;                   // [0,16)
            if (idx < 8) {
                int p = idx >> 2, sub = idx & 3;
                gsrc[t] = MallC_in + (size_t)(i0 + sub * 16 + lrow) * 2048 + s * 1024 + p * 32 + lk8;
                ldst[t] = SM + p * 2048 + sub * 512;
            } else {
                int i2 = idx - 8;
                int p = i2 >> 2, sub = i2 & 3;
                gsrc[t] = MT + (size_t)s * 262144 + (size_t)(j0 + sub * 16 + lrow) * 512 + p * 32 + lk8;
                ldst[t] = SM + 4096 + p * 2048 + sub * 512;
            }
        }
        f32x4 acc[2][2] = {};
        // prologue: stage tile 0 into buf 0 (no sync yet)
#pragma unroll
        for (int t = 0; t < 4; ++t) gl2lds16(gsrc[t], ldst[t]);
#pragma unroll 2
        for (int kk = 0; kk < 8; ++kk) {
            const int cb = (kk & 1) * 8192, nb = cb ^ 8192;
            __syncthreads();                 // waits tile kk's loads only
            if (kk < 7) {
#pragma unroll
                for (int t = 0; t < 4; ++t)
                    gl2lds16(gsrc[t] + (kk + 1) * 64, ldst[t] + nb);
            }
#pragma unroll
            for (int p = 0; p < 2; ++p) {
                u16x8 af[2], bq[2];
#pragma unroll
                for (int f = 0; f < 2; ++f)
                    af[f] = *(const u16x8*)(SM + cb + p * 2048 + (wr * 2 + f) * 512 + lane * 8);
#pragma unroll
                for (int f = 0; f < 2; ++f)
                    bq[f] = *(const u16x8*)(SM + cb + 4096 + p * 2048 + (wc * 2 + f) * 512 + lane * 8);
#pragma unroll
                for (int fi = 0; fi < 2; ++fi)
#pragma unroll
                    for (int fj = 0; fj < 2; ++fj)
                        acc[fi][fj] = mfma16(af[fi], bq[fj], acc[fi][fj]);
            }
        }
#pragma unroll
        for (int fi = 0; fi < 2; ++fi)
#pragma unroll
            for (int fj = 0; fj < 2; ++fj)
#pragma unroll
                for (int rr = 0; rr < 4; ++rr) {
                    int n = i0 + wr * 32 + fi * 16 + q * 4 + rr;
                    int c = j0 + wc * 32 + fj * 16 + lrow;
                    MallC_out[(size_t)n * 2048 + (2 * s + 1) * 512 + c] = f2bf(acc[fi][fj][rr]);
                }
    }
}

// ---------------------------------------------------------------------------
// ysum: 1024 blocks (4/CU). kq = bid>>8, rt = bid&255: r0 = rt*64, b = rt>>3,
// n0 = r0&511. Tile 64r x 64o, K=512 (quarter), BK=64, 8 iters.
// Per iter: sync -> prefetch(kk+1) -> MFMA(kk).
// ---------------------------------------------------------------------------
__global__ __launch_bounds__(256, 4) void ysum(
    const u16* __restrict__ G, const u16* __restrict__ Z, float* __restrict__ Yh)
{
    __shared__ __align__(16) u16 SM[16384];          // 32 KB, 2 buffers
    const int tid = threadIdx.x, lane = tid & 63, wid = tid >> 6;
    const int wr = wid >> 1, wc = wid & 1;
    const int lrow = lane & 15, lk8 = (lane >> 4) * 8;
    const int bid = blockIdx.x;
    const int kq = bid >> 8, rt = bid & 255;
    const int r0 = rt * 64, b = rt >> 3, n0 = r0 & 511;

    const u16* gsrc[4]; u16* ldst[4];
#pragma unroll
    for (int t = 0; t < 4; ++t) {
        int idx = wid * 4 + t;
        if (idx < 8) {
            int p = idx >> 2, sub = idx & 3;
            gsrc[t] = G + (size_t)(n0 + sub * 16 + lrow) * 2048 + kq * 512 + p * 32 + lk8;
            ldst[t] = SM + p * 2048 + sub * 512;
        } else {
            int i2 = idx - 8;
            int p = i2 >> 2, sub = i2 & 3;
            gsrc[t] = Z + (size_t)(b * 64 + sub * 16 + lrow) * 2048 + kq * 512 + p * 32 + lk8;
            ldst[t] = SM + 4096 + p * 2048 + sub * 512;
        }
    }
    f32x4 acc[2][2] = {};
    // prologue: stage tile 0 into buf 0 (no sync yet)
#pragma unroll
    for (int t = 0; t < 4; ++t) gl2lds16(gsrc[t], ldst[t]);
#pragma unroll 2
    for (int kk = 0; kk < 8; ++kk) {
        const int cb = (kk & 1) * 8192, nb = cb ^ 8192;
        __syncthreads();                     // waits tile kk's loads only
        if (kk < 7) {
#pragma unroll
            for (int t = 0; t < 4; ++t)
                gl2lds16(gsrc[t] + (kk + 1) * 64, ldst[t] + nb);
        }
#pragma unroll
        for (int p = 0; p < 2; ++p) {
            u16x8 af[2], bq[2];
#pragma unroll
            for (int f = 0; f < 2; ++f)
                af[f] = *(const u16x8*)(SM + cb + p * 2048 + (wr * 2 + f) * 512 + lane * 8);
#pragma unroll
            for (int f = 0; f < 2; ++f)
                bq[f] = *(const u16x8*)(SM + cb + 4096 + p * 2048 + (wc * 2 + f) * 512 + lane * 8);
#pragma unroll
            for (int fi = 0; fi < 2; ++fi)
#pragma unroll
                for (int fj = 0; fj < 2; ++fj)
                    acc[fi][fj] = mfma16(af[fi], bq[fj], acc[fi][fj]);
        }
    }
    const int q = lane >> 4;
    float* Yk = Yh + (size_t)kq * R_ * 64;
#pragma unroll
    for (int fi = 0; fi < 2; ++fi)
#pragma unroll
        for (int fj = 0; fj < 2; ++fj)
#pragma unroll
            for (int rr = 0; rr < 4; ++rr) {
                int r2 = r0 + wr * 32 + fi * 16 + q * 4 + rr;
                int o  = wc * 32 + fj * 16 + lrow;
                Yk[(size_t)r2 * 64 + o] = acc[fi][fj][rr];
            }
}

// ---------------------------------------------------------------------------
// bn_part: grid 256, block j: rows j*64..+63, v = sum of 4 Yh quarters.
// Also writes Y = v so bn_out reads the sum once (fence-free fusion).
// ---------------------------------------------------------------------------
__global__ __launch_bounds__(256) void bn_part(
    const float* __restrict__ Yh, float* __restrict__ part, float* __restrict__ Y)
{
    const int blk = blockIdx.x, tid = threadIdx.x;
    const int o = tid & 63, g = tid >> 6;
    float s = 0.f, s2 = 0.f;
#pragma unroll
    for (int p = 0; p < 16; ++p) {
        int r = blk * 64 + p * 4 + g;
        size_t off = (size_t)r * 64 + o;
        float v = Yh[off] + Yh[(size_t)R_ * 64 + off]
                + Yh[(size_t)2 * R_ * 64 + off] + Yh[(size_t)3 * R_ * 64 + off];
        Y[off] = v;
        s += v; s2 += v * v;
    }
    __shared__ float ls[4][64], ls2[4][64];
    ls[g][o] = s; ls2[g][o] = s2;
    __syncthreads();
    if (tid < 64) {
        float t = 0.f, t2 = 0.f;
#pragma unroll
        for (int g2 = 0; g2 < 4; ++g2) { t += ls[g2][tid]; t2 += ls2[g2][tid]; }
        part[blk * 128 + tid]      = t;
        part[blk * 128 + 64 + tid] = t2;
    }
}

// ---------------------------------------------------------------------------
// bn_out: inline stats from partials, then normalize+relu+w2+b2 (reads Y).
// ---------------------------------------------------------------------------
__global__ __launch_bounds__(256) void bn_out(
    const float* __restrict__ Y, const float* __restrict__ part,
    const float* __restrict__ gamma, const float* __restrict__ beta,
    const float* __restrict__ w2, const float* __restrict__ b2,
    float* __restrict__ out)
{
    __shared__ float ys[64 * 68];
    __shared__ float w2s[64 * 65];
    __shared__ float red[4][64], red2[4][64];
    __shared__ float sa[64], sh[64];
    const int tid = threadIdx.x;
    const int r0 = blockIdx.x * 64;
    const int o = tid & 63, g = tid >> 6;
    {
        float s = 0.f, s2 = 0.f;
        for (int p = g; p < 256; p += 4) {
            s  += part[p * 128 + o];
            s2 += part[p * 128 + 64 + o];
        }
        red[g][o] = s; red2[g][o] = s2;
    }
#pragma unroll
    for (int i = 0; i < 16; ++i) {
        int idx = tid + i * 256;
        w2s[(idx >> 6) * 65 + (idx & 63)] = w2[idx];
    }
    __syncthreads();
    if (tid < 64) {
        float t0 = red[0][tid] + red[1][tid] + red[2][tid] + red[3][tid];
        float t2 = red2[0][tid] + red2[1][tid] + red2[2][tid] + red2[3][tid];
        float mean = t0 * (1.0f / R_);
        float var  = t2 * (1.0f / R_) - mean * mean;
        float a = rsqrtf(var + 1e-5f) * gamma[tid];
        sa[tid] = a;
        sh[tid] = beta[tid] - mean * a;
    }
    __syncthreads();
    {
        float a = sa[o], bsh = sh[o];
#pragma unroll
        for (int p = 0; p < 16; ++p) {
            int rl = p * 4 + g;
            size_t off = (size_t)(r0 + rl) * 64 + o;
            float v = Y[off];
            ys[o * 68 + rl] = fmaxf(fmaf(v, a, bsh), 0.f);
        }
    }
    __syncthreads();
    float acc[16];
    float bb = b2[o];
#pragma unroll
    for (int j = 0; j < 16; ++j) acc[j] = bb;
    for (int c = 0; c < 64; ++c) {
        float wv = w2s[o * 65 + c];
        const float* yr = ys + c * 68 + g * 16;
        f32x4 y0 = *(const f32x4*)(yr);
        f32x4 y1 = *(const f32x4*)(yr + 4);
        f32x4 y2 = *(const f32x4*)(yr + 8);
        f32x4 y3 = *(const f32x4*)(yr + 12);
#pragma unroll
        for (int j = 0; j < 4; ++j) {
            acc[j]      = fmaf(wv, y0[j], acc[j]);
            acc[4 + j]  = fmaf(wv, y1[j], acc[4 + j]);
            acc[8 + j]  = fmaf(wv, y2[j], acc[8 + j]);
            acc[12 + j] = fmaf(wv, y3[j], acc[12 + j]);
        }
    }
#pragma unroll
    for (int j = 0; j < 16; ++j)
        out[(size_t)(r0 + g * 16 + j) * OUT_ + o] = acc[j];
}

// ---------------------------------------------------------------------------
extern "C" void kernel_launch(void* const* d_in, const int* in_sizes, int n_in,
                              void* d_out, int out_size, void* d_ws, size_t ws_size,
                              hipStream_t stream)
{
    const float* x       = (const float*)d_in[0];
    const float* support = (const float*)d_in[1];
    const float* weight  = (const float*)d_in[2];
    const float* eps     = (const float*)d_in[3];
    const float* gamma   = (const float*)d_in[4];
    const float* beta    = (const float*)d_in[5];
    const float* w2      = (const float*)d_in[6];
    const float* b2      = (const float*)d_in[7];
    float* out = (float*)d_out;

    char* ws = (char*)d_ws;
    u16*   MallC = (u16*)(ws);                      //  2,097,152  [512][2048]
    u16*   MT    = (u16*)(ws + 2097152);            //  1,048,576
    u16*   Wt    = (u16*)(ws + 3145728);            //    393,216  [256][768]
    u16*   Z     = (u16*)(ws + 3538944);            //  8,388,608  [2048][2048]
    float* Yh    = (float*)(ws + 11927552);         // 16,777,216  (4 quarters)
    float* part  = (float*)(ws + 28704768);         //    131,072
    float* Y     = (float*)(ws + 28835840);         //  4,194,304  [16384][64]

    prep2  <<<1280, 256, 0, stream>>>(support, weight, eps, MallC, MT, Wt);
    zmsq   <<<384,  256, 0, stream>>>(Wt, x, MallC, MT, Z, MallC);
    ysum   <<<1024, 256, 0, stream>>>(MallC, Z, Yh);
    bn_part<<<256,  256, 0, stream>>>(Yh, part, Y);
    bn_out <<<256,  256, 0, stream>>>(Y, part, gamma, beta, w2, b2, out);
}

// Round 7
// 160.948 us; speedup vs baseline: 1.7254x; 1.0151x over previous
//
#include <hip/hip_runtime.h>
#include <hip/hip_bf16.h>
#include <cstddef>
#include <cstdint>

// GINConvFFT round 19: r18 + ysum/bn_part fusion (fence-free).
//   ysumY: grid 256 (one block per 64-row r-tile), 512 thr (8 waves),
//   K=2048 in ONE block (BK=128, 16 iters, 64 KB dbuf LDS). Block writes
//   final Y (f32) + BN sum/sumsq partials. Eliminates: Yh (16.8 MB write +
//   29.4 MB read), one kernel launch, bn_part ramp/tail. No cross-block
//   fences (r17 lesson: per-block __threadfence = L2 writeback storm).
//   prep2: MallC even col-slices=(1+eps)I+A_s; MT; Wt          (1280 blk)
//   zmsq : blocks 0-255: Z[(b*64+o)][k*512+m] = Wt . x_b^T (fused k)
//          blocks 256-383: MallC odd slices = M_s^2 (64x64 tiles)
//   ysumY: Y[r][o] = full-K MallC . Z^T + BN partials        (256 blk x 512)
//   bn_out : inline stats + normalize+relu+w2+b2 (reads Y)     (256 blk)
#define B_   32
#define N_   512
#define D_   768
#define OUT_ 64
#define R_   (B_ * N_)

typedef unsigned short u16;
typedef __bf16 bf16x8 __attribute__((ext_vector_type(8)));
typedef float  f32x4  __attribute__((ext_vector_type(4)));
typedef unsigned short u16x8 __attribute__((ext_vector_type(8)));

__device__ __forceinline__ u16 f2bf(float f) {
    __hip_bfloat16 h = __float2bfloat16(f);
    return __builtin_bit_cast(u16, h);
}

__device__ __forceinline__ f32x4 mfma16(u16x8 a, u16x8 b, f32x4 c) {
    return __builtin_amdgcn_mfma_f32_16x16x32_bf16(
        __builtin_bit_cast(bf16x8, a), __builtin_bit_cast(bf16x8, b), c, 0, 0, 0);
}

__device__ __forceinline__ void gl2lds16(const void* g, void* l) {
    __builtin_amdgcn_global_load_lds(
        (const __attribute__((address_space(1))) unsigned int*)g,
        (__attribute__((address_space(3))) unsigned int*)l, 16, 0, 0);
}

// ---------------------------------------------------------------------------
// prep2: [0,512) build M (even MallC col slices) + MT | [512,1280) build Wt
// ---------------------------------------------------------------------------
__global__ __launch_bounds__(256) void prep2(
    const float* __restrict__ support, const float* __restrict__ weight,
    const float* __restrict__ epsp,
    u16* __restrict__ MallC, u16* __restrict__ MT, u16* __restrict__ Wt)
{
    const int blk = blockIdx.x, tid = threadIdx.x;
    __shared__ float t[32][33];
    if (blk < 512) {
        int s = blk >> 8, rem = blk & 255;
        int n0 = (rem >> 4) * 32, m0 = (rem & 15) * 32;
        const float f = 1.0f + epsp[0];
        const float* S = support + (size_t)s * 262144;
#pragma unroll
        for (int p = 0; p < 4; ++p) {
            int nl = p * 8 + (tid >> 5), ml = tid & 31;
            float v = S[(size_t)(n0 + nl) * 512 + m0 + ml];
            if (n0 + nl == m0 + ml) v += f;
            MallC[(size_t)(n0 + nl) * 2048 + s * 1024 + m0 + ml] = f2bf(v);
            t[nl][ml] = v;
        }
        __syncthreads();
#pragma unroll
        for (int p = 0; p < 4; ++p) {
            int ml = p * 8 + (tid >> 5), nl = tid & 31;
            MT[(size_t)s * 262144 + (size_t)(m0 + ml) * 512 + n0 + nl] = f2bf(t[nl][ml]);
        }
    } else {
        int idx = (blk - 512) * 256 + tid;          // 4*64*768 = 196608
        int k = idx / 49152, rem = idx % 49152;
        int o = rem / 768, d = rem % 768;
        int l = d >> 6, hh = d & 63;
        Wt[idx] = f2bf(weight[((size_t)l * 256 + hh * 4 + k) * 64 + o]);
    }
}

// ---------------------------------------------------------------------------
// zmsq: fused-k zgemm + msq, 80 KB LDS, 2 blocks/CU max. (unchanged r18)
// ---------------------------------------------------------------------------
__global__ __launch_bounds__(256, 2) void zmsq(
    const u16* __restrict__ Wt, const float* __restrict__ x,
    const u16* __restrict__ MallC_in, const u16* __restrict__ MT,
    u16* __restrict__ Z, u16* __restrict__ MallC_out)
{
    __shared__ __align__(16) u16 SM[40960];          // 80 KB
    const int tid = threadIdx.x, lane = tid & 63, wid = tid >> 6;
    const int lrow = lane & 15, lk8 = (lane >> 4) * 8;
    const int q = lane >> 4;
    const int bid = blockIdx.x;

    if (bid < 256) {
        // ---------------- fused-k zgemm ----------------
        const int b = bid >> 3, m0 = (bid & 7) * 64;
        u16* Abuf = SM;
        u16* Bbuf = SM + 32768;

        const u16* gsrcA[8]; u16* ldstA[8];
#pragma unroll
        for (int t = 0; t < 8; ++t) {
            int idx = wid * 8 + t;                   // [0,32)
            int p = idx >> 4, g = idx & 15;
            gsrcA[t] = Wt + (size_t)(g * 16 + lrow) * 768 + p * 32 + lk8;
            ldstA[t] = Abuf + p * 8192 + g * 512;
        }
        const int r = tid >> 2, c4 = tid & 3;
        const float* gx = x + (size_t)(b * 512 + m0 + r) * 768 + c4 * 16;
        u16* bdst = Bbuf + (c4 >> 1) * 2048 + (r >> 4) * 512
                  + (c4 & 1) * 256 + (r & 15) * 8;

        f32x4 acc[4][4] = {};

        // ---- prologue: stage tile 0 into buf 0 (no sync yet) ----
        {
            f32x4 a0 = *(const f32x4*)(gx);
            f32x4 a1 = *(const f32x4*)(gx + 4);
            f32x4 a2 = *(const f32x4*)(gx + 8);
            f32x4 a3 = *(const f32x4*)(gx + 12);
#pragma unroll
            for (int t = 0; t < 8; ++t) gl2lds16(gsrcA[t], ldstA[t]);
            u16x8 w0, w1;
#pragma unroll
            for (int j = 0; j < 4; ++j) {
                w0[j] = f2bf(a0[j]); w0[4 + j] = f2bf(a1[j]);
                w1[j] = f2bf(a2[j]); w1[4 + j] = f2bf(a3[j]);
            }
            *(u16x8*)(bdst)       = w0;
            *(u16x8*)(bdst + 128) = w1;
        }

        // ---- main loop: sync -> prefetch(kk+1) -> MFMA(kk) -> write B ----
#pragma unroll 2
        for (int kk = 0; kk < 12; ++kk) {
            const int cbA = (kk & 1) * 16384, nbA = cbA ^ 16384;
            const int cbB = (kk & 1) * 4096,  nbB = cbB ^ 4096;
            __syncthreads();                 // waits tile kk's loads only
            f32x4 a0, a1, a2, a3;
            if (kk < 11) {
                const float* g = gx + (kk + 1) * 64;
                a0 = *(const f32x4*)(g);
                a1 = *(const f32x4*)(g + 4);
                a2 = *(const f32x4*)(g + 8);
                a3 = *(const f32x4*)(g + 12);
#pragma unroll
                for (int t = 0; t < 8; ++t)
                    gl2lds16(gsrcA[t] + (kk + 1) * 64, ldstA[t] + nbA);
            }
#pragma unroll
            for (int p = 0; p < 2; ++p) {
                u16x8 af[4], bq[4];
#pragma unroll
                for (int f = 0; f < 4; ++f)
                    af[f] = *(const u16x8*)(Abuf + cbA + p * 8192 + (wid * 4 + f) * 512 + lane * 8);
#pragma unroll
                for (int f = 0; f < 4; ++f)
                    bq[f] = *(const u16x8*)(Bbuf + cbB + p * 2048 + f * 512 + lane * 8);
#pragma unroll
                for (int fi = 0; fi < 4; ++fi)
#pragma unroll
                    for (int fj = 0; fj < 4; ++fj)
                        acc[fi][fj] = mfma16(af[fi], bq[fj], acc[fi][fj]);
            }
            if (kk < 11) {
                u16x8 w0, w1;
#pragma unroll
                for (int j = 0; j < 4; ++j) {
                    w0[j] = f2bf(a0[j]); w0[4 + j] = f2bf(a1[j]);
                    w1[j] = f2bf(a2[j]); w1[4 + j] = f2bf(a3[j]);
                }
                *(u16x8*)(bdst + nbB)       = w0;
                *(u16x8*)(bdst + nbB + 128) = w1;
            }
        }
        __syncthreads();                     // all MFMA reads done before reuse

        // ---- epilogue: repack [256 rows][72 stride] in LDS, coalesced store
        u16* scr = SM;
#pragma unroll
        for (int fi = 0; fi < 4; ++fi)
#pragma unroll
            for (int fj = 0; fj < 4; ++fj)
#pragma unroll
                for (int rr = 0; rr < 4; ++rr)
                    scr[(wid * 64 + fi * 16 + q * 4 + rr) * 72 + fj * 16 + lrow]
                        = f2bf(acc[fi][fj][rr]);
        __syncthreads();
        const int c8 = (tid & 7) * 8, rg = tid >> 3;     // rg in [0,32)
#pragma unroll
        for (int i = 0; i < 8; ++i) {
            int srow = i * 32 + rg;                      // [0,256)
            u16x8 v = *(const u16x8*)(scr + srow * 72 + c8);
            int o = srow & 63, k = srow >> 6;
            *(u16x8*)(Z + (size_t)(b * 64 + o) * 2048 + k * 512 + m0 + c8) = v;
        }
    } else {
        // ---------------- msq ----------------
        const int lb = bid - 256;
        const int s = lb >> 6, i0 = ((lb >> 3) & 7) * 64, j0 = (lb & 7) * 64;
        const int wr = wid >> 1, wc = wid & 1;

        const u16* gsrc[4]; u16* ldst[4];
#pragma unroll
        for (int t = 0; t < 4; ++t) {
            int idx = wid * 4 + t;                   // [0,16)
            if (idx < 8) {
                int p = idx >> 2, sub = idx & 3;
                gsrc[t] = MallC_in + (size_t)(i0 + sub * 16 + lrow) * 2048 + s * 1024 + p * 32 + lk8;
                ldst[t] = SM + p * 2048 + sub * 512;
            } else {
                int i2 = idx - 8;
                int p = i2 >> 2, sub = i2 & 3;
                gsrc[t] = MT + (size_t)s * 262144 + (size_t)(j0 + sub * 16 + lrow) * 512 + p * 32 + lk8;
                ldst[t] = SM + 4096 + p * 2048 + sub * 512;
            }
        }
        f32x4 acc[2][2] = {};
#pragma unroll
        for (int t = 0; t < 4; ++t) gl2lds16(gsrc[t], ldst[t]);
#pragma unroll 2
        for (int kk = 0; kk < 8; ++kk) {
            const int cb = (kk & 1) * 8192, nb = cb ^ 8192;
            __syncthreads();                 // waits tile kk's loads only
            if (kk < 7) {
#pragma unroll
                for (int t = 0; t < 4; ++t)
                    gl2lds16(gsrc[t] + (kk + 1) * 64, ldst[t] + nb);
            }
#pragma unroll
            for (int p = 0; p < 2; ++p) {
                u16x8 af[2], bq[2];
#pragma unroll
                for (int f = 0; f < 2; ++f)
                    af[f] = *(const u16x8*)(SM + cb + p * 2048 + (wr * 2 + f) * 512 + lane * 8);
#pragma unroll
                for (int f = 0; f < 2; ++f)
                    bq[f] = *(const u16x8*)(SM + cb + 4096 + p * 2048 + (wc * 2 + f) * 512 + lane * 8);
#pragma unroll
                for (int fi = 0; fi < 2; ++fi)
#pragma unroll
                    for (int fj = 0; fj < 2; ++fj)
                        acc[fi][fj] = mfma16(af[fi], bq[fj], acc[fi][fj]);
            }
        }
#pragma unroll
        for (int fi = 0; fi < 2; ++fi)
#pragma unroll
            for (int fj = 0; fj < 2; ++fj)
#pragma unroll
                for (int rr = 0; rr < 4; ++rr) {
                    int n = i0 + wr * 32 + fi * 16 + q * 4 + rr;
                    int c = j0 + wc * 32 + fj * 16 + lrow;
                    MallC_out[(size_t)n * 2048 + (2 * s + 1) * 512 + c] = f2bf(acc[fi][fj][rr]);
                }
    }
}

// ---------------------------------------------------------------------------
// ysumY: grid 256 x 512 thr. Block rt: rows r0 = rt*64 (b = rt>>3,
// n0 = (rt&7)*64), full K=2048, BK=128, 16 iters, 64 KB dbuf LDS.
// Waves 2x4 (wr row-half, wc 16-o-col). Epilogue: Y + BN partials.
// ---------------------------------------------------------------------------
__global__ __launch_bounds__(512) void ysumY(
    const u16* __restrict__ G, const u16* __restrict__ Z,
    float* __restrict__ Y, float* __restrict__ part)
{
    __shared__ __align__(16) u16 SM[32768];          // 64 KB: 2 x (A16K + B16K)
    const int tid = threadIdx.x, lane = tid & 63, wid = tid >> 6;  // wid 0..7
    const int wr = wid >> 2, wc = wid & 3;
    const int lrow = lane & 15, lk8 = (lane >> 4) * 8;
    const int rt = blockIdx.x;
    const int r0 = rt * 64, b = rt >> 3, n0 = (rt & 7) * 64;

    // 32 subtile-loads (16 A + 16 B), 4 per wave. Per buffer (16384 u16):
    // A: p*2048 + sub*512 (p k-panel of 32, sub 16-row). B: +8192 same.
    const u16* gsrc[4]; u16* ldst[4];
#pragma unroll
    for (int t = 0; t < 4; ++t) {
        int idx = wid * 4 + t;                       // [0,32)
        if (idx < 16) {
            int p = idx >> 2, sub = idx & 3;
            gsrc[t] = G + (size_t)(n0 + sub * 16 + lrow) * 2048 + p * 32 + lk8;
            ldst[t] = SM + p * 2048 + sub * 512;
        } else {
            int i2 = idx - 16;
            int p = i2 >> 2, sub = i2 & 3;
            gsrc[t] = Z + (size_t)(b * 64 + sub * 16 + lrow) * 2048 + p * 32 + lk8;
            ldst[t] = SM + 8192 + p * 2048 + sub * 512;
        }
    }
    f32x4 acc[2] = {};
    // prologue: stage tile 0 into buf 0 (no sync yet)
#pragma unroll
    for (int t = 0; t < 4; ++t) gl2lds16(gsrc[t], ldst[t]);
#pragma unroll 2
    for (int kk = 0; kk < 16; ++kk) {
        const int cb = (kk & 1) * 16384, nb = cb ^ 16384;
        __syncthreads();                     // waits tile kk's loads only
        if (kk < 15) {
#pragma unroll
            for (int t = 0; t < 4; ++t)
                gl2lds16(gsrc[t] + (kk + 1) * 128, ldst[t] + nb);
        }
#pragma unroll
        for (int p = 0; p < 4; ++p) {
            u16x8 bq = *(const u16x8*)(SM + cb + 8192 + p * 2048 + wc * 512 + lane * 8);
#pragma unroll
            for (int f = 0; f < 2; ++f) {
                u16x8 af = *(const u16x8*)(SM + cb + p * 2048 + (wr * 2 + f) * 512 + lane * 8);
                acc[f] = mfma16(af, bq, acc[f]);
            }
        }
    }
    __syncthreads();                         // last MFMA reads done

    // ---- epilogue: stage C into LDS f32 [64][68], then Y + stats ----
    float* ls = (float*)SM;                  // 64*68*4 = 17408 B
    const int q = lane >> 4;
#pragma unroll
    for (int f = 0; f < 2; ++f)
#pragma unroll
        for (int rr = 0; rr < 4; ++rr)
            ls[(wr * 32 + f * 16 + q * 4 + rr) * 68 + wc * 16 + lrow] = acc[f][rr];
    __syncthreads();
    const int o = tid & 63, g = tid >> 6;    // g in [0,8), 8 rows/thread
    float s = 0.f, s2 = 0.f;
#pragma unroll
    for (int pp = 0; pp < 8; ++pp) {
        int rr2 = pp * 8 + g;
        float v = ls[rr2 * 68 + o];
        Y[(size_t)(r0 + rr2) * 64 + o] = v;
        s += v; s2 += v * v;
    }
    float* rs  = (float*)(SM + 16384);       // 8*64 f32 @ byte 32768
    float* rs2 = rs + 512;
    rs[g * 64 + o] = s; rs2[g * 64 + o] = s2;
    __syncthreads();
    if (tid < 64) {
        float t1 = 0.f, t2 = 0.f;
#pragma unroll
        for (int gg = 0; gg < 8; ++gg) { t1 += rs[gg * 64 + tid]; t2 += rs2[gg * 64 + tid]; }
        part[rt * 128 + tid]      = t1;
        part[rt * 128 + 64 + tid] = t2;
    }
}

// ---------------------------------------------------------------------------
// bn_out: inline stats from partials, then normalize+relu+w2+b2 (reads Y).
// ---------------------------------------------------------------------------
__global__ __launch_bounds__(256) void bn_out(
    const float* __restrict__ Y, const float* __restrict__ part,
    const float* __restrict__ gamma, const float* __restrict__ beta,
    const float* __restrict__ w2, const float* __restrict__ b2,
    float* __restrict__ out)
{
    __shared__ float ys[64 * 68];
    __shared__ float w2s[64 * 65];
    __shared__ float red[4][64], red2[4][64];
    __shared__ float sa[64], sh[64];
    const int tid = threadIdx.x;
    const int r0 = blockIdx.x * 64;
    const int o = tid & 63, g = tid >> 6;
    {
        float s = 0.f, s2 = 0.f;
        for (int p = g; p < 256; p += 4) {
            s  += part[p * 128 + o];
            s2 += part[p * 128 + 64 + o];
        }
        red[g][o] = s; red2[g][o] = s2;
    }
#pragma unroll
    for (int i = 0; i < 16; ++i) {
        int idx = tid + i * 256;
        w2s[(idx >> 6) * 65 + (idx & 63)] = w2[idx];
    }
    __syncthreads();
    if (tid < 64) {
        float t0 = red[0][tid] + red[1][tid] + red[2][tid] + red[3][tid];
        float t2 = red2[0][tid] + red2[1][tid] + red2[2][tid] + red2[3][tid];
        float mean = t0 * (1.0f / R_);
        float var  = t2 * (1.0f / R_) - mean * mean;
        float a = rsqrtf(var + 1e-5f) * gamma[tid];
        sa[tid] = a;
        sh[tid] = beta[tid] - mean * a;
    }
    __syncthreads();
    {
        float a = sa[o], bsh = sh[o];
#pragma unroll
        for (int p = 0; p < 16; ++p) {
            int rl = p * 4 + g;
            size_t off = (size_t)(r0 + rl) * 64 + o;
            float v = Y[off];
            ys[o * 68 + rl] = fmaxf(fmaf(v, a, bsh), 0.f);
        }
    }
    __syncthreads();
    float acc[16];
    float bb = b2[o];
#pragma unroll
    for (int j = 0; j < 16; ++j) acc[j] = bb;
    for (int c = 0; c < 64; ++c) {
        float wv = w2s[o * 65 + c];
        const float* yr = ys + c * 68 + g * 16;
        f32x4 y0 = *(const f32x4*)(yr);
        f32x4 y1 = *(const f32x4*)(yr + 4);
        f32x4 y2 = *(const f32x4*)(yr + 8);
        f32x4 y3 = *(const f32x4*)(yr + 12);
#pragma unroll
        for (int j = 0; j < 4; ++j) {
            acc[j]      = fmaf(wv, y0[j], acc[j]);
            acc[4 + j]  = fmaf(wv, y1[j], acc[4 + j]);
            acc[8 + j]  = fmaf(wv, y2[j], acc[8 + j]);
            acc[12 + j] = fmaf(wv, y3[j], acc[12 + j]);
        }
    }
#pragma unroll
    for (int j = 0; j < 16; ++j)
        out[(size_t)(r0 + g * 16 + j) * OUT_ + o] = acc[j];
}

// ---------------------------------------------------------------------------
extern "C" void kernel_launch(void* const* d_in, const int* in_sizes, int n_in,
                              void* d_out, int out_size, void* d_ws, size_t ws_size,
                              hipStream_t stream)
{
    const float* x       = (const float*)d_in[0];
    const float* support = (const float*)d_in[1];
    const float* weight  = (const float*)d_in[2];
    const float* eps     = (const float*)d_in[3];
    const float* gamma   = (const float*)d_in[4];
    const float* beta    = (const float*)d_in[5];
    const float* w2      = (const float*)d_in[6];
    const float* b2      = (const float*)d_in[7];
    float* out = (float*)d_out;

    char* ws = (char*)d_ws;
    u16*   MallC = (u16*)(ws);                      //  2,097,152  [512][2048]
    u16*   MT    = (u16*)(ws + 2097152);            //  1,048,576
    u16*   Wt    = (u16*)(ws + 3145728);            //    393,216  [256][768]
    u16*   Z     = (u16*)(ws + 3538944);            //  8,388,608  [2048][2048]
    float* part  = (float*)(ws + 28704768);         //    131,072
    float* Y     = (float*)(ws + 28835840);         //  4,194,304  [16384][64]

    prep2  <<<1280, 256, 0, stream>>>(support, weight, eps, MallC, MT, Wt);
    zmsq   <<<384,  256, 0, stream>>>(Wt, x, MallC, MT, Z, MallC);
    ysumY  <<<256,  512, 0, stream>>>(MallC, Z, Y, part);
    bn_out <<<256,  256, 0, stream>>>(Y, part, gamma, beta, w2, b2, out);
}